// Round 10
// baseline (300.219 us; speedup 1.0000x reference)
//
#include <hip/hip_runtime.h>
#include <cstdint>
#include <cstddef>

typedef unsigned short u16;
typedef unsigned int   u32;
typedef unsigned long long u64;
typedef __attribute__((ext_vector_type(8))) short short8;   // 8 bf16 = 4 VGPR
typedef __attribute__((ext_vector_type(4))) float f32x4;

#define M_ROWS 16384
#define N_COLS 256
#define IN_F   1024
#define K_SPL  8192   // 1024 features * 8 basis
#define K_TOT  9216   // + 1024 base (silu) features
// BK=64 chunks: 144 total (128 spline chunks of 8 features, 16 base chunks of 64 feats)
#define NCHUNK 144
#define SPLITK 2
#define CPB    (NCHUNK / SPLITK)   // 72 chunks per block

// ---------- helpers ----------
__device__ __forceinline__ u32 f2bf1(float f) {          // f32 -> bf16 bits, RNE
  u32 u = __float_as_uint(f);
  u += 0x7fffu + ((u >> 16) & 1u);
  return u >> 16;
}
__device__ __forceinline__ u32 pk2(float a, float b) {
  return f2bf1(a) | (f2bf1(b) << 16);
}
__device__ __forceinline__ float silu(float v) {
  return v * __builtin_amdgcn_rcpf(1.f + __expf(-v));
}

// 8 bf16 cubic B-spline basis values for one x, packed as uint4 (16B).
__device__ __forceinline__ uint4 basis8(float xv) {
  float u = fmaf(xv, 2.5f, 5.5f);
  int i0 = (int)u;
  float fr = u - (float)i0;
  float fr2 = fr * fr, fr3 = fr2 * fr;
  float om  = 1.f - fr;
  float om3 = om * om * om;
  float w0 = om3 * (1.f / 6.f);
  float w3 = fr3 * (1.f / 6.f);
  float w1 = fmaf(fr3, 0.5f, fmaf(fr2, -1.f, 2.f / 3.f));
  float w2 = fmaf(fr + fr2 - fr3, 0.5f, 1.f / 6.f);
  u64 W = (u64)pk2(w0, w1) | ((u64)pk2(w2, w3) << 32);
  if (!(u >= 0.f && u < 11.f)) W = 0ull;
  int s = (i0 - 3) * 16;
  u64 lo, hi;
  if (s >= 64)      { int r = s - 64; lo = 0ull; hi = (r < 64) ? (W << r) : 0ull; }
  else if (s > 0)   { lo = W << s;    hi = W >> (64 - s); }
  else if (s == 0)  { lo = W;         hi = 0ull; }
  else              { int r = -s;     lo = (r < 64) ? (W >> r) : 0ull; hi = 0ull; }
  uint4 o;
  o.x = (u32)lo; o.y = (u32)(lo >> 32); o.z = (u32)hi; o.w = (u32)(hi >> 32);
  return o;
}

// ---------- kernel 1: pack weights into FRAGMENT-MAJOR bf16 layout ----------
// Bq unit t = ((c*2 + h)*16 + colf)*64 + lane; 16B per unit.
// col = colf*16 + (lane&15); k = c*64 + h*32 + (lane>>4)*8 + e  (e=0..7).
// k<8192 -> spline weight [col][k] (= [col][feat*8+basis]); else base [col][k-8192].
// A wave's B-fragment load becomes 64 lanes x contiguous 16B = 1KB coalesced.
__global__ void pack_weights(const float* __restrict__ bw, const float* __restrict__ sw,
                             u16* __restrict__ Bq) {
  int t    = blockIdx.x * blockDim.x + threadIdx.x;   // 0 .. 294911
  int lane = t & 63;
  int rest = t >> 6;          // 0..4607
  int colf = rest & 15;
  int hc   = rest >> 4;       // c*2 + h, 0..287
  int col  = colf * 16 + (lane & 15);
  int kk   = (hc >> 1) * 64 + (hc & 1) * 32 + (lane >> 4) * 8;
  const float* src = (kk < K_SPL) ? (sw + (size_t)col * K_SPL + kk)
                                  : (bw + (size_t)col * IN_F + (kk - K_SPL));
  uint4 v;
  v.x = pk2(src[0], src[1]);
  v.y = pk2(src[2], src[3]);
  v.z = pk2(src[4], src[5]);
  v.w = pk2(src[6], src[7]);
  *(uint4*)(Bq + (size_t)t * 8) = v;
}

// ---------- kernel 2: fused KAN GEMM — ZERO LDS, ZERO BARRIERS ----------
// R10 theory: R4 = LDS-BW-bound (400KB/CU/chunk); R7/R9 = barrier/latency
// bound. Kill both: (1) A-fragment for lane l IS basis8(x[row][c*8+h*4+kg])
// -> computed in registers, no A staging/LDS (costs 4x redundancy across the
// 4 n-waves = ~17us device VALU, affordable); (2) B pre-packed fragment-major
// -> per-fragment load = 64 lanes x contiguous 16B = coalesced 1KB straight
// to VGPR (B L2 traffic 1.15GB = same as R4's glds path). No __shared__, no
// __syncthreads, waves fully independent -> deep natural pipelining.
// Geometry: wave = 64x64 tile, acc[4][4]=64 regs (VGPR cap 256 @ 2 waves/SIMD
// -> no spill trap); block = 4 waves = 64 rows x 256 cols; split-K=2 adjacent
// partners (2 atomic writers/line, R4-proven); grid 512 x 256 thr = 2 blk/CU.
// kid=0: chunks 0..71 (all spline). kid=1: 72..127 spline + 128..143 base.
__global__ __launch_bounds__(256, 2)
void kan_gemm(const float* __restrict__ x, const u16* __restrict__ Bq,
              float* __restrict__ out) {
  const int tid  = threadIdx.x;
  const int lane = tid & 63;
  const int w    = tid >> 6;          // 0..3 = n-tile (64 cols)
  const int lm   = lane & 15;
  const int kg   = lane >> 4;         // 0..3

  const int bid  = blockIdx.x;        // 512
  const int kid  = bid & 1;
  const int row0 = (bid >> 1) * 64;
  const int cs   = kid * CPB;

  f32x4 acc[4][4];
#pragma unroll
  for (int i = 0; i < 4; ++i)
#pragma unroll
    for (int j = 0; j < 4; ++j)
      acc[i][j] = (f32x4){0.f, 0.f, 0.f, 0.f};

  // per-lane base pointers
  const float* xr = x + (size_t)(row0 + lm) * IN_F;          // + i*16*IN_F rows
  const u16*   Bw = Bq + ((size_t)(w * 4) * 64 + lane) * 8;  // + (c*32+h*16+j)*512

  auto LOADB = [&](int c, short8* bf) {   // bf[8] = [h*4+j], 8x coalesced 1KB
    const u16* p = Bw + (size_t)c * (32 * 512);
#pragma unroll
    for (int h = 0; h < 2; ++h)
#pragma unroll
      for (int j = 0; j < 4; ++j)
        bf[h * 4 + j] = *(const short8*)(p + (h * 16 + j) * 512);
  };

  auto LXS = [&](int c, float* pxv) {     // spline x: 8 scalars [i*2+h]
#pragma unroll
    for (int i = 0; i < 4; ++i) {
      const float* p = xr + i * (16 * IN_F) + c * 8 + kg;
      pxv[i * 2 + 0] = p[0];              // h=0: feature c*8 + kg
      pxv[i * 2 + 1] = p[4];              // h=1: feature c*8 + 4 + kg
    }
  };

  auto SPL = [&](const float* pxv, const short8* bf) {   // spline chunk compute
#pragma unroll
    for (int h = 0; h < 2; ++h) {
      short8 af[4];
#pragma unroll
      for (int i = 0; i < 4; ++i) {
        uint4 q = basis8(pxv[i * 2 + h]);
        af[i] = *(const short8*)&q;
      }
#pragma unroll
      for (int i = 0; i < 4; ++i)
#pragma unroll
        for (int j = 0; j < 4; ++j)
          acc[i][j] = __builtin_amdgcn_mfma_f32_16x16x32_bf16(af[i], bf[h * 4 + j], acc[i][j], 0, 0, 0);
    }
  };

  auto BASEC = [&](int c, const short8* bf) {            // base (silu) chunk
#pragma unroll
    for (int h = 0; h < 2; ++h)
#pragma unroll
      for (int i = 0; i < 4; ++i) {
        const float* p = xr + i * (16 * IN_F) + (c - 128) * 64 + h * 32 + kg * 8;
        float4 a  = *(const float4*)p;
        float4 b2 = *(const float4*)(p + 4);
        uint4 q;
        q.x = pk2(silu(a.x),  silu(a.y));
        q.y = pk2(silu(a.z),  silu(a.w));
        q.z = pk2(silu(b2.x), silu(b2.y));
        q.w = pk2(silu(b2.z), silu(b2.w));
        short8 af = *(const short8*)&q;
#pragma unroll
        for (int j = 0; j < 4; ++j)
          acc[i][j] = __builtin_amdgcn_mfma_f32_16x16x32_bf16(af, bf[h * 4 + j], acc[i][j], 0, 0, 0);
      }
  };

  float  pxA[8], pxB[8];
  short8 bfA[8], bfB[8];

  // ---- spline loop: kid0 [0,72), kid1 [72,128); counts 72/56, both even ----
  const int se = kid ? 128 : 72;
  LXS(cs, pxA); LOADB(cs, bfA);
  for (int c = cs; c < se; c += 2) {
    LXS(c + 1, pxB); LOADB(c + 1, bfB);     // prefetch c+1
    SPL(pxA, bfA);
    if (c + 2 < se) { LXS(c + 2, pxA); LOADB(c + 2, bfA); }  // prefetch c+2
    SPL(pxB, bfB);
  }

  // ---- base loop (kid=1 only): [128,144), 16 chunks, x2 unrolled ----
  if (kid) {
    LOADB(128, bfA);
    for (int c = 128; c < 144; c += 2) {
      LOADB(c + 1, bfB);
      BASEC(c, bfA);
      if (c + 2 < 144) LOADB(c + 2, bfA);
      BASEC(c + 1, bfB);
    }
  }

  // ---- epilogue: C/D col=lane&15, row=(lane>>4)*4+reg; split-K=2 -> 2 atomic writers ----
  const int lc = lane & 15;
  const int lr = (lane >> 4) * 4;
#pragma unroll
  for (int i = 0; i < 4; ++i) {
#pragma unroll
    for (int j = 0; j < 4; ++j) {
      int gr = row0 + i * 16 + lr;
      int gc = w * 64 + j * 16 + lc;
      float* po = out + (size_t)gr * N_COLS + gc;
#pragma unroll
      for (int r = 0; r < 4; ++r)
        unsafeAtomicAdd(po + (size_t)r * N_COLS, acc[i][j][r]);
    }
  }
}

extern "C" void kernel_launch(void* const* d_in, const int* in_sizes, int n_in,
                              void* d_out, int out_size, void* d_ws, size_t ws_size,
                              hipStream_t stream) {
  const float* x  = (const float*)d_in[0];   // 16384 x 1024
  const float* bw = (const float*)d_in[1];   // 256 x 1024
  const float* sw = (const float*)d_in[2];   // 256 x 8192
  float* out = (float*)d_out;                // 16384 x 256 f32
  u16* Bq = (u16*)d_ws;                      // 4.5 MB fragment-major

  hipMemsetAsync(d_out, 0, (size_t)M_ROWS * N_COLS * sizeof(float), stream);

  // 294912 16B-units / 256 thr = 1152 blocks
  pack_weights<<<1152, 256, 0, stream>>>(bw, sw, Bq);

  kan_gemm<<<512, 256, 0, stream>>>(x, Bq, out);
}

// Round 11
// 216.546 us; speedup vs baseline: 1.3864x; 1.3864x over previous
//
#include <hip/hip_runtime.h>
#include <cstdint>
#include <cstddef>

typedef unsigned short u16;
typedef unsigned int   u32;
typedef unsigned long long u64;
typedef __attribute__((ext_vector_type(8))) short short8;   // 8 bf16 = 4 VGPR
typedef __attribute__((ext_vector_type(4))) float f32x4;

#define M_ROWS 16384
#define N_COLS 256
#define IN_F   1024
#define K_SPL  8192   // 1024 features * 8 basis
#define K_TOT  9216   // + 1024 base (silu) features
// BK=64 chunks: 144 total (128 spline chunks of 8 features, 16 base chunks of 64 feats)
#define NCHUNK 144
#define SPLITK 2
#define CPB    (NCHUNK / SPLITK)   // 72 chunks per block

// ---------- helpers ----------
__device__ __forceinline__ u32 f2bf1(float f) {          // f32 -> bf16 bits, RNE
  u32 u = __float_as_uint(f);
  u += 0x7fffu + ((u >> 16) & 1u);
  return u >> 16;
}
__device__ __forceinline__ u32 pk2(float a, float b) {
  return f2bf1(a) | (f2bf1(b) << 16);
}
__device__ __forceinline__ float silu(float v) {
  return v * __builtin_amdgcn_rcpf(1.f + __expf(-v));
}

// 8 bf16 cubic B-spline basis values for one x, packed as uint4 (16B).
__device__ __forceinline__ uint4 basis8(float xv) {
  float u = fmaf(xv, 2.5f, 5.5f);
  int i0 = (int)u;
  float fr = u - (float)i0;
  float fr2 = fr * fr, fr3 = fr2 * fr;
  float om  = 1.f - fr;
  float om3 = om * om * om;
  float w0 = om3 * (1.f / 6.f);
  float w3 = fr3 * (1.f / 6.f);
  float w1 = fmaf(fr3, 0.5f, fmaf(fr2, -1.f, 2.f / 3.f));
  float w2 = fmaf(fr + fr2 - fr3, 0.5f, 1.f / 6.f);
  u64 W = (u64)pk2(w0, w1) | ((u64)pk2(w2, w3) << 32);
  if (!(u >= 0.f && u < 11.f)) W = 0ull;
  int s = (i0 - 3) * 16;
  u64 lo, hi;
  if (s >= 64)      { int r = s - 64; lo = 0ull; hi = (r < 64) ? (W << r) : 0ull; }
  else if (s > 0)   { lo = W << s;    hi = W >> (64 - s); }
  else if (s == 0)  { lo = W;         hi = 0ull; }
  else              { int r = -s;     lo = (r < 64) ? (W >> r) : 0ull; hi = 0ull; }
  uint4 o;
  o.x = (u32)lo; o.y = (u32)(lo >> 32); o.z = (u32)hi; o.w = (u32)(hi >> 32);
  return o;
}

// ---------- kernel 1: pack weights FRAGMENT-MAJOR (R10-proven) + zero out ----------
// Bq unit t = ((c*2 + h)*16 + colf)*64 + lane; 16B per unit.
// col = colf*16 + (lane&15); k = c*64 + h*32 + (lane>>4)*8 + e.
__global__ void pack_weights(const float* __restrict__ bw, const float* __restrict__ sw,
                             u16* __restrict__ Bq, float* __restrict__ out) {
  int t    = blockIdx.x * blockDim.x + threadIdx.x;   // 0 .. 294911
  int lane = t & 63;
  int rest = t >> 6;
  int colf = rest & 15;
  int hc   = rest >> 4;       // c*2 + h, 0..287
  int col  = colf * 16 + (lane & 15);
  int kk   = (hc >> 1) * 64 + (hc & 1) * 32 + (lane >> 4) * 8;
  const float* src = (kk < K_SPL) ? (sw + (size_t)col * K_SPL + kk)
                                  : (bw + (size_t)col * IN_F + (kk - K_SPL));
  uint4 v;
  v.x = pk2(src[0], src[1]);
  v.y = pk2(src[2], src[3]);
  v.z = pk2(src[4], src[5]);
  v.w = pk2(src[6], src[7]);
  *(uint4*)(Bq + (size_t)t * 8) = v;

  // zero the output (replaces the hipMemsetAsync dispatch)
  float4 z = {0.f, 0.f, 0.f, 0.f};
  float4* o4 = (float4*)out;
  const int tot = M_ROWS * N_COLS / 4;           // 1,048,576
  for (int i = t; i < tot; i += gridDim.x * blockDim.x) o4[i] = z;
}

// ---------- kernel 2: fused KAN GEMM — tiny LDS (A only), B from L2 ----------
// R11 synthesis: R4's wall = LDS-instr throughput (320 b128/CU/chunk x 12cy x 72
// = 115us). R10 calibrated basis8 ~100 VALU instrs -> A MUST be built once per
// block (LDS), but B can come straight from L2 in fragment-major layout IF
// wave tiles are 64x64 (B-read redundancy 4 waves -> 1.18GB L2 = 34us, fits
// per-kid 2.25MB slice in per-XCD L2). Geometry: 256 thr = 4 waves (64x64 each,
// acc[4][4]=64), __launch_bounds__(256,4) -> VGPR cap 128 (bf JIT per h keeps
// ~120, no R5/R6 spill trap), 4 INDEPENDENT blocks/CU = 16 waves/CU (no R9
// lockstep). LDS = As dbuf 16KB only; 8 ds_reads + 2 ds_writes per wave/chunk
// (vs R4's 10+glds). Barriers are lgkm-only raw s_barrier + sched_barrier(0)
// (rule #18) — NO vmcnt(0) drain in the loop (B/x loads are register-private).
// Builders: thread t -> row t>>2, slots t&3 and (t&3)+4, every chunk (2 uint4
// writes). Spline x prefetched 2 chunks ahead (pxA/pxB by parity, static
// unroll x2); base chunks (kid=1, c>=128, 16 of them) load x JIT in BUILD.
// Split-K=2 adjacent partners -> 2 atomic writers/line (R4-proven benign).
__global__ __launch_bounds__(256, 4)
void kan_gemm(const float* __restrict__ x, const u16* __restrict__ Bq,
              float* __restrict__ out) {
  __shared__ __align__(16) u16 As[2 * 64 * 64];   // 16 KB (2 bufs)

  const int tid  = threadIdx.x;
  const int lane = tid & 63;
  const int wn   = tid >> 6;          // 0..3: n-tile (64 cols)
  const int lm   = lane & 15;
  const int kg   = lane >> 4;         // 0..3

  const int bid  = blockIdx.x;        // 512
  const int kid  = bid & 1;
  const int row0 = (bid >> 1) * 64;
  const int cs   = kid * CPB, c1 = cs + CPB;   // 72 chunks, cs in {0,72}

  f32x4 acc[4][4];
#pragma unroll
  for (int i = 0; i < 4; ++i)
#pragma unroll
    for (int j = 0; j < 4; ++j)
      acc[i][j] = (f32x4){0.f, 0.f, 0.f, 0.f};

  // builder: thread t -> row br, 16B slots bq and bq+4 (R4 swizzle)
  const int br = tid >> 2;            // 0..63
  const int bq = tid & 3;
  const int a_wr0 = br * 64 + ((bq ^ (br & 7)) * 8);
  const int a_wr1 = br * 64 + (((bq + 4) ^ (br & 7)) * 8);
  const float* xr = x + (size_t)(row0 + br) * IN_F;

  // A-frag read offsets: rows i*16+lm, slot kg (h=0) / kg^4 (h=1, = ^32)
  int a_off[4];
#pragma unroll
  for (int i = 0; i < 4; ++i) {
    int ra = i * 16 + lm;
    a_off[i] = ra * 64 + ((kg ^ (ra & 7)) * 8);
  }

  // B fragment-major base: frag (c, h, j) at Bw + c*32*512 + (h*16 + wn*4 + j)*512
  const u16* Bw = Bq + ((size_t)(wn * 4) * 64 + lane) * 8;

  float pxA0, pxA1, pxB0, pxB1;

  auto LOADX = [&](int c, float& p0, float& p1) {   // spline only (c < 128)
    p0 = xr[c * 8 + bq];
    p1 = xr[c * 8 + bq + 4];
  };

  auto BUILD = [&](int c, int buf, float p0, float p1) {
    uint4 q0, q1;
    if (c < 128) {
      q0 = basis8(p0);
      q1 = basis8(p1);
    } else {                                        // base chunk: JIT x loads
      const float* xp0 = xr + (c - 128) * 64 + bq * 8;
      const float* xp1 = xr + (c - 128) * 64 + (bq + 4) * 8;
      float4 a = *(const float4*)xp0, b = *(const float4*)(xp0 + 4);
      float4 d = *(const float4*)xp1, e = *(const float4*)(xp1 + 4);
      q0.x = pk2(silu(a.x), silu(a.y)); q0.y = pk2(silu(a.z), silu(a.w));
      q0.z = pk2(silu(b.x), silu(b.y)); q0.w = pk2(silu(b.z), silu(b.w));
      q1.x = pk2(silu(d.x), silu(d.y)); q1.y = pk2(silu(d.z), silu(d.w));
      q1.z = pk2(silu(e.x), silu(e.y)); q1.w = pk2(silu(e.z), silu(e.w));
    }
    u16* Ab = As + buf * (64 * 64);
    *(uint4*)(Ab + a_wr0) = q0;
    *(uint4*)(Ab + a_wr1) = q1;
  };

  auto CHUNK = [&](int c, int buf) {
    const u16* Ab = As + buf * (64 * 64);
    const u16* Bc = Bw + (size_t)c * (32 * 512);
#pragma unroll
    for (int h = 0; h < 2; ++h) {
      short8 bf[4], af[4];
#pragma unroll
      for (int j = 0; j < 4; ++j) bf[j] = *(const short8*)(Bc + (h * 16 + j) * 512);
#pragma unroll
      for (int i = 0; i < 4; ++i) af[i] = *(const short8*)(Ab + (a_off[i] ^ (h * 32)));
      __builtin_amdgcn_s_setprio(1);
#pragma unroll
      for (int i = 0; i < 4; ++i)
#pragma unroll
        for (int j = 0; j < 4; ++j)
          acc[i][j] = __builtin_amdgcn_mfma_f32_16x16x32_bf16(af[i], bf[j], acc[i][j], 0, 0, 0);
      __builtin_amdgcn_s_setprio(0);
    }
  };

  // lgkm-only barrier: ds_writes visible, NO vmcnt drain; sched_barrier per rule #18
#define BAR() do { asm volatile("s_waitcnt lgkmcnt(0)" ::: "memory"); \
                   __builtin_amdgcn_s_barrier(); \
                   __builtin_amdgcn_sched_barrier(0); } while (0)

  // ---- prologue: chunk cs -> buf0; px for cs+1 in flight ----
  LOADX(cs, pxA0, pxA1);                 // cs = 0 or 72, always spline
  BUILD(cs, 0, pxA0, pxA1);
  LOADX(cs + 1, pxB0, pxB1);             // cs+1 <= 73 < 128, spline
  BAR();

  // ---- main loop: x2 unrolled (CPB=72 even), 1 lgkm-barrier per chunk ----
  for (int c = cs; c < c1; c += 2) {
    // chunk c (buf0); build c+1 -> buf1
    if (c + 1 < c1) BUILD(c + 1, 1, pxB0, pxB1);
    if (c + 2 < c1 && c + 2 < 128) LOADX(c + 2, pxA0, pxA1);
    CHUNK(c, 0);
    BAR();

    // chunk c+1 (buf1); build c+2 -> buf0
    if (c + 1 < c1) {
      if (c + 2 < c1) BUILD(c + 2, 0, pxA0, pxA1);
      if (c + 3 < c1 && c + 3 < 128) LOADX(c + 3, pxB0, pxB1);
      CHUNK(c + 1, 1);
      BAR();
    }
  }
#undef BAR

  // ---- epilogue: C/D col=lane&15, row=(lane>>4)*4+reg; split-K=2 -> 2 atomic writers ----
  const int lc = lane & 15;
  const int lr = (lane >> 4) * 4;
#pragma unroll
  for (int i = 0; i < 4; ++i) {
#pragma unroll
    for (int j = 0; j < 4; ++j) {
      int gr = row0 + i * 16 + lr;
      int gc = wn * 64 + j * 16 + lc;
      float* po = out + (size_t)gr * N_COLS + gc;
#pragma unroll
      for (int r = 0; r < 4; ++r)
        unsafeAtomicAdd(po + (size_t)r * N_COLS, acc[i][j][r]);
    }
  }
}

extern "C" void kernel_launch(void* const* d_in, const int* in_sizes, int n_in,
                              void* d_out, int out_size, void* d_ws, size_t ws_size,
                              hipStream_t stream) {
  const float* x  = (const float*)d_in[0];   // 16384 x 1024
  const float* bw = (const float*)d_in[1];   // 256 x 1024
  const float* sw = (const float*)d_in[2];   // 256 x 8192
  float* out = (float*)d_out;                // 16384 x 256 f32
  u16* Bq = (u16*)d_ws;                      // 4.5 MB fragment-major

  // pack_weights also zeroes `out` (stream-ordered before kan_gemm)
  pack_weights<<<1152, 256, 0, stream>>>(bw, sw, Bq, out);

  kan_gemm<<<512, 256, 0, stream>>>(x, Bq, out);
}